// Round 4
// baseline (83.430 us; speedup 1.0000x reference)
//
#include <hip/hip_runtime.h>
#include <hip/hip_bf16.h>

namespace {

constexpr int B_N = 8;
constexpr int A_N = 100000;
constexpr int M_N = 128;
constexpr int BLOCK = 256;
constexpr int NBLK = (A_N + BLOCK - 1) / BLOCK;  // 391
constexpr int NBALL = B_N * NBLK;                // 3128 blocks total
constexpr int CHUNK = (NBALL + BLOCK - 1) / BLOCK;  // 13

// workspace layout (bytes)
constexpr size_t OFF_BOX  = 0;                                   // B*M*8 f
constexpr size_t OFF_K1P  = OFF_BOX + (size_t)B_N * M_N * 8 * 4; // 3128*2 f
constexpr size_t OFF_BAL  = OFF_K1P + (size_t)NBALL * 2 * 4;     // 3128*4 u64
constexpr size_t OFF_BASE = OFF_BAL + (size_t)NBALL * 4 * 8;     // 3129 u32
constexpr size_t OFF_INP  = (OFF_BASE + (size_t)(NBALL + 1) * 4 + 15) & ~size_t(15);  // 8 f
constexpr size_t OFF_PPART= OFF_INP + 8 * 4;                     // 256*3 f
constexpr size_t OFF_LIST = (OFF_PPART + 256 * 3 * 4 + 15) & ~size_t(15);  // rest: u32 list

// ---------------------------------------------------------------------------
// K0: box2d records {x1,y1,x2,y2,area,pad,pad,pad}; invalid boxes get
// coords (+1e30,+1e30,-1e30,-1e30), area 0 -> inter=0, can never drive pos.
// ---------------------------------------------------------------------------
__global__ void k0_prep(const float* __restrict__ ann_, float* __restrict__ boxbuf)
{
    const int i = blockIdx.x * blockDim.x + threadIdx.x;
    if (i >= B_N * M_N) return;
    const float* t = ann_ + (size_t)i * 18;
    float minx = t[0], maxx = t[0], miny = t[1], maxy = t[1];
#pragma unroll
    for (int j = 1; j < 8; ++j) {
        const float xj = t[2 * j], yj = t[2 * j + 1];
        minx = fminf(minx, xj); maxx = fmaxf(maxx, xj);
        miny = fminf(miny, yj); maxy = fmaxf(maxy, yj);
    }
    float area = (maxx - minx) * (maxy - miny);
    if (t[17] < 0.0f) {
        minx = 1e30f; miny = 1e30f; maxx = -1e30f; maxy = -1e30f; area = 0.0f;
    }
    float* o = boxbuf + (size_t)i * 8;
    o[0] = minx; o[1] = miny; o[2] = maxx; o[3] = maxy;
    o[4] = area; o[5] = 0.f;  o[6] = 0.f;  o[7] = 0.f;
}

// ---------------------------------------------------------------------------
// K1: hot kernel. Band tests only (no argmax, no divides, no cndmask chain):
//   m1 = max_m(3*in - aarea - ba)  -> pos iff m1 >= 0   (iou >= 0.5)
//   m2 = max_m(m1term + 0.5*in)    -> neg iff m2 <  0   (iou <  0.4)
// 14 VALU/pair, loop-carried dep = one v_max. Boxes broadcast from LDS.
// Outputs: per-block {cls_neg_sum_raw, pos_count}, per-wave pos ballot.
// ---------------------------------------------------------------------------
__global__ __launch_bounds__(BLOCK) void k1_main(
    const float* __restrict__ cls_,
    const float* __restrict__ anchors_,
    const float* __restrict__ boxbuf,
    float* __restrict__ k1part,                  // (3128, 2)
    unsigned long long* __restrict__ ballots)    // (3128, 4)
{
    __shared__ float4 s_bb[M_N];
    __shared__ float  s_ba[M_N];

    const int b = blockIdx.y, blk = blockIdx.x, tid = threadIdx.x;
    if (tid < M_N) {
        const float4* rec = (const float4*)(boxbuf + ((size_t)b * M_N + tid) * 8);
        s_bb[tid] = rec[0];
        s_ba[tid] = rec[1].x;
    }
    __syncthreads();

    const int a  = blk * BLOCK + tid;
    const int ca = min(a, A_N - 1);
    const float4 an = ((const float4*)anchors_)[ca];
    const float naarea = -(an.z - an.x) * (an.w - an.y);

    float m1 = -1e30f, m2 = -1e30f;
#pragma unroll 8
    for (int m = 0; m < M_N; m += 2) {
        const float4 b0 = s_bb[m];     const float a0 = s_ba[m];
        const float4 b1 = s_bb[m + 1]; const float a1 = s_ba[m + 1];

        const float iw0 = fminf(an.z, b0.z) - fmaxf(an.x, b0.x);
        const float ih0 = fminf(an.w, b0.w) - fmaxf(an.y, b0.y);
        const float in0 = fmaxf(iw0, 0.f) * fmaxf(ih0, 0.f);
        const float q10 = __builtin_fmaf(3.0f, in0, naarea) - a0;
        const float q20 = __builtin_fmaf(0.5f, in0, q10);

        const float iw1 = fminf(an.z, b1.z) - fmaxf(an.x, b1.x);
        const float ih1 = fminf(an.w, b1.w) - fmaxf(an.y, b1.y);
        const float in1 = fmaxf(iw1, 0.f) * fmaxf(ih1, 0.f);
        const float q11 = __builtin_fmaf(3.0f, in1, naarea) - a1;
        const float q21 = __builtin_fmaf(0.5f, in1, q11);

        m1 = fmaxf(m1, fmaxf(q10, q11));   // may fuse to v_max3
        m2 = fmaxf(m2, fmaxf(q20, q21));
    }

    const bool inb = (a < A_N);
    const bool pos = inb && (m1 >= 0.0f);
    const bool neg = (m2 < 0.0f);

    // focal "all-negative-targets" term; pos anchors get corrected in K4.
    float clsS = 0.0f;
    {
        const float* cp = cls_ + ((size_t)b * A_N + ca) * 8;
        const float4 cA = ((const float4*)cp)[0];
        const float4 cB = ((const float4*)cp)[1];
        const float pv[8] = {cA.x, cA.y, cA.z, cA.w, cB.x, cB.y, cB.z, cB.w};
        float sneg = 0.f;
#pragma unroll
        for (int c = 0; c < 8; ++c) {
            const float p = fminf(fmaxf(pv[c], 1e-4f), 1.0f - 1e-4f);
            sneg += 0.75f * p * p * (-__logf(1.0f - p));
        }
        clsS = (inb && (pos || neg)) ? sneg : 0.0f;
    }

    const unsigned long long word = __ballot(pos);
    const int wv = tid >> 6, ln = tid & 63;
    const int idx = b * NBLK + blk;

#pragma unroll
    for (int off = 32; off; off >>= 1) clsS += __shfl_down(clsS, off);

    __shared__ float s_c[4];
    __shared__ unsigned s_p[4];
    if (ln == 0) {
        s_c[wv] = clsS;
        s_p[wv] = (unsigned)__popcll(word);
        ballots[(size_t)idx * 4 + wv] = word;
    }
    __syncthreads();
    if (tid == 0) {
        const float    C = s_c[0] + s_c[1] + s_c[2] + s_c[3];
        const unsigned P = s_p[0] + s_p[1] + s_p[2] + s_p[3];
        k1part[(size_t)idx * 2 + 0] = C;
        k1part[(size_t)idx * 2 + 1] = (float)P;
    }
}

// ---------------------------------------------------------------------------
// K2: one-block exclusive scan of per-block pos counts -> list base offsets,
// per-image num_pos -> inv_np. base[3128] = total_pos.
// ---------------------------------------------------------------------------
__global__ __launch_bounds__(BLOCK) void k2_scan(
    const float* __restrict__ k1part,
    unsigned* __restrict__ base,     // 3129
    float* __restrict__ inv_np)      // 8
{
    __shared__ unsigned s_sum[BLOCK];
    const int t = threadIdx.x;
    const int j0 = t * CHUNK;
    unsigned c[CHUNK];
    unsigned T = 0;
#pragma unroll
    for (int k = 0; k < CHUNK; ++k) {
        const int j = j0 + k;
        const unsigned v = (j < NBALL) ? (unsigned)k1part[(size_t)j * 2 + 1] : 0u;
        c[k] = v; T += v;
    }
    s_sum[t] = T;
    __syncthreads();
    for (int off = 1; off < BLOCK; off <<= 1) {
        const unsigned v = (t >= off) ? s_sum[t - off] : 0u;
        __syncthreads();
        s_sum[t] += v;
        __syncthreads();
    }
    unsigned run = s_sum[t] - T;  // exclusive prefix
#pragma unroll
    for (int k = 0; k < CHUNK; ++k) {
        const int j = j0 + k;
        if (j < NBALL) base[j] = run;
        run += c[k];
    }
    if (t == BLOCK - 1) base[NBALL] = s_sum[BLOCK - 1];
    __syncthreads();
    if (t < B_N) {
        const unsigned np = base[(t + 1) * NBLK] - base[t * NBLK];
        inv_np[t] = 1.0f / fmaxf((float)np, 1.0f);
    }
}

// ---------------------------------------------------------------------------
// K3: compact pos anchors into dense list (deterministic order: b, blk, lane).
// ---------------------------------------------------------------------------
__global__ __launch_bounds__(BLOCK) void k3_compact(
    const unsigned long long* __restrict__ ballots,
    const unsigned* __restrict__ base,
    unsigned* __restrict__ list)
{
    __shared__ unsigned long long s_w[4];
    const int b = blockIdx.y, blk = blockIdx.x, tid = threadIdx.x;
    const int idx = b * NBLK + blk;
    if (tid < 4) s_w[tid] = ballots[(size_t)idx * 4 + tid];
    __syncthreads();
    const int wv = tid >> 6, ln = tid & 63;
    const unsigned long long w = s_w[wv];
    if ((w >> ln) & 1ull) {
        unsigned pre = 0;
        if (wv > 0) pre += (unsigned)__popcll(s_w[0]);
        if (wv > 1) pre += (unsigned)__popcll(s_w[1]);
        if (wv > 2) pre += (unsigned)__popcll(s_w[2]);
        const unsigned rank = (unsigned)__popcll(w & ((1ull << ln) - 1ull));
        const unsigned p = base[idx] + pre + rank;
        list[p] = ((unsigned)b << 20) | (unsigned)(blk * BLOCK + tid);
    }
}

// ---------------------------------------------------------------------------
// K4: dense pos pass. Per pos anchor: 128-box argmax (first-wins, division-
// free, same as validated R3), then cls correction + reg + vp, scaled by
// 1/num_pos of its image. Grid-stride; block partials in fixed slots.
// ---------------------------------------------------------------------------
__global__ __launch_bounds__(BLOCK) void k4_pos(
    const float* __restrict__ cls_,
    const float* __restrict__ reg_,
    const float* __restrict__ anchors_,
    const float* __restrict__ ann_,
    const float* __restrict__ boxbuf,
    const unsigned* __restrict__ base,
    const float* __restrict__ inv_np,
    const unsigned* __restrict__ list,
    float* __restrict__ pospart)     // (256, 3)
{
    const int tid = threadIdx.x;
    const int total = (int)base[NBALL];
    float clsS = 0.f, regS = 0.f, vpS = 0.f;

    for (int i = blockIdx.x * BLOCK + tid; i < total; i += 256 * BLOCK) {
        const unsigned e = list[i];
        const int b = (int)(e >> 20);
        const int a = (int)(e & 0xFFFFFu);

        const float4 an = ((const float4*)anchors_)[a];
        const float aarea = (an.z - an.x) * (an.w - an.y);
        const float* bx = boxbuf + (size_t)b * M_N * 8;

        float bn = 0.f, bs = 1.f;
        int   kb = 0;
        for (int m = 0; m < M_N; ++m) {
            const float4 bb = ((const float4*)bx)[m * 2];
            const float  ba = bx[m * 8 + 4];
            const float iw = fminf(an.z, bb.z) - fmaxf(an.x, bb.x);
            const float ih = fminf(an.w, bb.w) - fmaxf(an.y, bb.y);
            const float in_ = fmaxf(iw, 0.f) * fmaxf(ih, 0.f);
            const float s = aarea + ba;
            const bool u = in_ * bs > bn * s;   // iou_m > iou_best, first-wins
            bn = u ? in_ : bn;
            bs = u ? s   : bs;
            kb = u ? m   : kb;
        }

        const float inv = inv_np[b];
        const float* t = ann_ + ((size_t)b * M_N + kb) * 18;
        float tt[16];
#pragma unroll
        for (int j = 0; j < 16; ++j) tt[j] = t[j];
        const int kc = (int)t[17];

        // cls correction: replace the "negative" term of class kc with the
        // positive focal term.
        const float praw = cls_[((size_t)b * A_N + a) * 8 + kc];
        const float p = fminf(fmaxf(praw, 1e-4f), 1.0f - 1e-4f);
        const float negkc   = 0.75f * p * p * (-__logf(1.0f - p));
        const float posterm = 0.25f * (1.0f - p) * (1.0f - p) * (-__logf(p));
        clsS += (posterm - negkc) * inv;

        // reg + vp (validated R3 epilogue)
        const float aw  = an.z - an.x;
        const float ah  = an.w - an.y;
        const float acx = an.x + 0.5f * aw;
        const float acy = an.y + 0.5f * ah;
        const float* rp = reg_ + ((size_t)b * A_N + a) * 8;
        const float4 r0 = ((const float4*)rp)[0];
        const float4 r1 = ((const float4*)rp)[1];

        auto vp = [](float rx, float ry, float tx, float ty) {
            const float denom = sqrtf(rx * rx + ry * ry) * sqrtf(tx * tx + ty * ty);
            return 1.0f - (rx * tx + ry * ty) / fmaxf(denom, 1e-8f);
        };
        const float vp1 = vp(r0.z, r0.w,
            (tt[4] + tt[6] + tt[12] + tt[14] - (tt[0] + tt[2] + tt[8] + tt[10])) * 0.25f,
            (tt[5] + tt[7] + tt[13] + tt[15] - (tt[1] + tt[3] + tt[9] + tt[11])) * 0.25f);
        const float vp2 = vp(r1.x, r1.y,
            (tt[2] + tt[6] + tt[10] + tt[14] - (tt[0] + tt[4] + tt[8] + tt[12])) * 0.25f,
            (tt[3] + tt[7] + tt[11] + tt[15] - (tt[1] + tt[5] + tt[9] + tt[13])) * 0.25f);
        const float vp3 = vp(r1.z, r1.w,
            (tt[0] + tt[2] + tt[4] + tt[6] - (tt[8] + tt[10] + tt[12] + tt[14])) * 0.25f,
            (tt[1] + tt[3] + tt[5] + tt[7] - (tt[9] + tt[11] + tt[13] + tt[15])) * 0.25f);
        vpS += (vp1 + vp2 + vp3) * (1.0f / 3.0f) * inv;

        const float s2[8] = {-1, -1, 1, 1, -1, -1, 1, 1};
        const float s4[8] = {-1, 1, -1, 1, -1, 1, -1, 1};
        const float s6[8] = {1, 1, 1, 1, -1, -1, -1, -1};
        float ssum = 0.f;
#pragma unroll
        for (int j = 0; j < 8; ++j) {
            const float px = r0.x + r0.z * s2[j] + r1.x * s4[j] + r1.z * s6[j];
            const float py = r0.y + r0.w * s2[j] + r1.y * s4[j] + r1.w * s6[j];
            const float tx = (tt[2 * j]     - acx) / aw;
            const float ty = (tt[2 * j + 1] - acy) / ah;
            const float dx = fabsf(px - tx);
            const float dy = fabsf(py - ty);
            ssum += (dx <= (1.0f / 9.0f)) ? 4.5f * dx * dx : dx - (0.5f / 9.0f);
            ssum += (dy <= (1.0f / 9.0f)) ? 4.5f * dy * dy : dy - (0.5f / 9.0f);
        }
        regS += ssum * (1.0f / 16.0f) * inv;
    }

    // deterministic block reduce
#pragma unroll
    for (int off = 32; off; off >>= 1) {
        clsS += __shfl_down(clsS, off);
        regS += __shfl_down(regS, off);
        vpS  += __shfl_down(vpS,  off);
    }
    __shared__ float s_r[4][3];
    const int wv = tid >> 6, ln = tid & 63;
    if (ln == 0) { s_r[wv][0] = clsS; s_r[wv][1] = regS; s_r[wv][2] = vpS; }
    __syncthreads();
    if (tid == 0) {
        float C = 0, R = 0, V = 0;
        for (int w = 0; w < 4; ++w) { C += s_r[w][0]; R += s_r[w][1]; V += s_r[w][2]; }
        pospart[(size_t)blockIdx.x * 3 + 0] = C;
        pospart[(size_t)blockIdx.x * 3 + 1] = R;
        pospart[(size_t)blockIdx.x * 3 + 2] = V;
    }
}

// ---------------------------------------------------------------------------
// K5: final reduce. cls = (sum_blk k1part_cls*inv_np[img] + sum pos_corr)/8.
// ---------------------------------------------------------------------------
__global__ __launch_bounds__(BLOCK) void k5_final(
    const float* __restrict__ k1part,
    const float* __restrict__ pospart,
    const float* __restrict__ inv_np,
    float* __restrict__ out)
{
    const int t = threadIdx.x;
    float cs = 0.f, rs = 0.f, vs = 0.f;
    for (int i = t; i < NBALL; i += BLOCK) {
        const int b = i / NBLK;
        cs += k1part[(size_t)i * 2] * inv_np[b];
    }
    if (t < 256) {
        cs += pospart[(size_t)t * 3 + 0];
        rs += pospart[(size_t)t * 3 + 1];
        vs += pospart[(size_t)t * 3 + 2];
    }
#pragma unroll
    for (int off = 32; off; off >>= 1) {
        cs += __shfl_down(cs, off);
        rs += __shfl_down(rs, off);
        vs += __shfl_down(vs, off);
    }
    __shared__ float s_r[4][3];
    const int wv = t >> 6, ln = t & 63;
    if (ln == 0) { s_r[wv][0] = cs; s_r[wv][1] = rs; s_r[wv][2] = vs; }
    __syncthreads();
    if (t == 0) {
        float C = 0, R = 0, V = 0;
        for (int w = 0; w < 4; ++w) { C += s_r[w][0]; R += s_r[w][1]; V += s_r[w][2]; }
        out[0] = C * 0.125f;
        out[1] = R * 0.125f;
        out[2] = V * 0.125f;
    }
}

}  // namespace

extern "C" void kernel_launch(void* const* d_in, const int* in_sizes, int n_in,
                              void* d_out, int out_size, void* d_ws, size_t ws_size,
                              hipStream_t stream)
{
    const float* cls_    = (const float*)d_in[0];
    const float* reg_    = (const float*)d_in[1];
    const float* anchors = (const float*)d_in[2];
    const float* ann     = (const float*)d_in[3];
    // d_in[4] embeddings: unused by the reference.

    char* ws = (char*)d_ws;
    float*              boxbuf  = (float*)(ws + OFF_BOX);
    float*              k1part  = (float*)(ws + OFF_K1P);
    unsigned long long* ballots = (unsigned long long*)(ws + OFF_BAL);
    unsigned*           base    = (unsigned*)(ws + OFF_BASE);
    float*              inv_np  = (float*)(ws + OFF_INP);
    float*              pospart = (float*)(ws + OFF_PPART);
    unsigned*           list    = (unsigned*)(ws + OFF_LIST);

    k0_prep<<<dim3((B_N * M_N + BLOCK - 1) / BLOCK), dim3(BLOCK), 0, stream>>>(ann, boxbuf);
    k1_main<<<dim3(NBLK, B_N), dim3(BLOCK), 0, stream>>>(cls_, anchors, boxbuf,
                                                         k1part, ballots);
    k2_scan<<<dim3(1), dim3(BLOCK), 0, stream>>>(k1part, base, inv_np);
    k3_compact<<<dim3(NBLK, B_N), dim3(BLOCK), 0, stream>>>(ballots, base, list);
    k4_pos<<<dim3(256), dim3(BLOCK), 0, stream>>>(cls_, reg_, anchors, ann, boxbuf,
                                                  base, inv_np, list, pospart);
    k5_final<<<dim3(1), dim3(BLOCK), 0, stream>>>(k1part, pospart, inv_np, (float*)d_out);
}